// Round 1
// baseline (397.604 us; speedup 1.0000x reference)
//
#include <hip/hip_runtime.h>
#include <float.h>
#include <stdint.h>

constexpr int D_MODEL = 1024;
constexpr int DICT    = 16384;
constexpr int TOPK    = 8;
constexpr int NCAND   = 16;
constexpr int NTOK    = 4096;      // B*T
constexpr int NTILE   = 128;       // DICT / 128
constexpr long long COEFF_COUNT = (long long)NTOK * DICT;

typedef __attribute__((ext_vector_type(8))) __bf16 bf16x8;
typedef __attribute__((ext_vector_type(4))) float  floatx4;

__device__ __forceinline__ unsigned short f2bf(float f) {
    unsigned int u = __float_as_uint(f);
    u = u + 0x7fffu + ((u >> 16) & 1u);     // RNE
    return (unsigned short)(u >> 16);
}

__device__ __forceinline__ void async16(void* lds, const void* g) {
    __builtin_amdgcn_global_load_lds(
        (__attribute__((address_space(1))) void*)g,
        (__attribute__((address_space(3))) void*)lds, 16, 0, 0);
}

// ---------------------------------------------------------------------------
// fused fp32 -> bf16 convert for x and Wenc (one dispatch)
// ---------------------------------------------------------------------------
__global__ __launch_bounds__(256) void ssod_cvt2(const float4* __restrict__ xs, ushort4* __restrict__ xd, int nx4,
                                                 const float4* __restrict__ ws, ushort4* __restrict__ wd, int nw4) {
    const int i = blockIdx.x * 256 + threadIdx.x;
    if (i < nx4) {
        const float4 v = xs[i];
        ushort4 o; o.x = f2bf(v.x); o.y = f2bf(v.y); o.z = f2bf(v.z); o.w = f2bf(v.w);
        xd[i] = o;
    } else {
        const int j = i - nx4;
        if (j < nw4) {
            const float4 v = ws[j];
            ushort4 o; o.x = f2bf(v.x); o.y = f2bf(v.y); o.z = f2bf(v.z); o.w = f2bf(v.w);
            wd[j] = o;
        }
    }
}

// ---------------------------------------------------------------------------
// 256x256-tile, 8-wave, 8-phase-style bf16 MFMA GEMM with 4-slot LDS ring
// (BK=32/slot), counted vmcnt (never 0 in steady state), XOR-swizzled LDS,
// setprio around MFMA clusters, XCD-aware block swizzle.
// Epilogue: bf16 C-write + per-128-col tile-max (mono16 = bf ^ 0x8000).
// Numerics identical to previous version (bf16 in, fp32 MFMA acc, same K order).
// ---------------------------------------------------------------------------
constexpr size_t R1OFF = (size_t)128 * (D_MODEL * 2);   // +128 rows in global

#define STAGE_A(buf_, t_) do {                                               \
    const char* s_ = pA + (size_t)(t_) * 64;                                 \
    char* d_ = (char*)&As[(buf_)][0] + wave * 1024;                          \
    async16(d_, s_); async16(d_ + 8192, s_ + R1OFF);                         \
} while (0)

#define STAGE_B(buf_, t_) do {                                               \
    const char* s_ = pB + (size_t)(t_) * 64;                                 \
    char* d_ = (char*)&Bs[(buf_)][0] + wave * 1024;                          \
    async16(d_, s_); async16(d_ + 8192, s_ + R1OFF);                         \
} while (0)

#define MFMA4(a_, r_)                                                                        \
    acc[r_][0] = __builtin_amdgcn_mfma_f32_16x16x32_bf16(a_, bq0, acc[r_][0], 0, 0, 0);      \
    acc[r_][1] = __builtin_amdgcn_mfma_f32_16x16x32_bf16(a_, bq1, acc[r_][1], 0, 0, 0);      \
    acc[r_][2] = __builtin_amdgcn_mfma_f32_16x16x32_bf16(a_, bq2, acc[r_][2], 0, 0, 0);      \
    acc[r_][3] = __builtin_amdgcn_mfma_f32_16x16x32_bf16(a_, bq3, acc[r_][3], 0, 0, 0);

#define TILE_BODY(T_, DOSTAGE_)                                              \
  {                                                                          \
    const int buf_ = (T_) & 3;                                               \
    const char* ab_ = (const char*)As + buf_ * 16384 + aob;                  \
    const char* bb_ = (const char*)Bs + buf_ * 16384 + bob;                  \
    bf16x8 af0 = *(const bf16x8*)(ab_);                                      \
    bf16x8 af1 = *(const bf16x8*)(ab_ + 1024);                               \
    bf16x8 af2 = *(const bf16x8*)(ab_ + 2048);                               \
    bf16x8 af3 = *(const bf16x8*)(ab_ + 3072);                               \
    bf16x8 bq0 = *(const bf16x8*)(bb_);                                      \
    bf16x8 bq1 = *(const bf16x8*)(bb_ + 1024);                               \
    bf16x8 bq2 = *(const bf16x8*)(bb_ + 2048);                               \
    bf16x8 bq3 = *(const bf16x8*)(bb_ + 3072);                               \
    if (DOSTAGE_) { STAGE_A(((T_) + 3) & 3, (T_) + 3); }                     \
    __builtin_amdgcn_s_barrier();                                            \
    asm volatile("s_waitcnt lgkmcnt(0)" ::: "memory");                       \
    __builtin_amdgcn_s_setprio(1);                                           \
    MFMA4(af0, 0); MFMA4(af1, 1); MFMA4(af2, 2); MFMA4(af3, 3);              \
    __builtin_amdgcn_s_setprio(0);                                           \
    __builtin_amdgcn_s_barrier();                                            \
    bf16x8 ag0 = *(const bf16x8*)(ab_ + 4096);                               \
    bf16x8 ag1 = *(const bf16x8*)(ab_ + 5120);                               \
    bf16x8 ag2 = *(const bf16x8*)(ab_ + 6144);                               \
    bf16x8 ag3 = *(const bf16x8*)(ab_ + 7168);                               \
    if (DOSTAGE_) { STAGE_B(((T_) + 3) & 3, (T_) + 3); }                     \
    __builtin_amdgcn_s_barrier();                                            \
    asm volatile("s_waitcnt lgkmcnt(0)" ::: "memory");                       \
    __builtin_amdgcn_s_setprio(1);                                           \
    MFMA4(ag0, 4); MFMA4(ag1, 5); MFMA4(ag2, 6); MFMA4(ag3, 7);              \
    __builtin_amdgcn_s_setprio(0);                                           \
  }

#define TILE_CLOSE(VMI)                                                      \
    asm volatile("s_waitcnt vmcnt(" #VMI ")" ::: "memory");                  \
    __builtin_amdgcn_s_barrier();

__global__ __launch_bounds__(512, 2) void ssod_gemm_bf16(const unsigned short* __restrict__ A,
                                                         const unsigned short* __restrict__ B,
                                                         unsigned short* __restrict__ C,
                                                         unsigned short* __restrict__ tmax,
                                                         int mtiles) {
    __shared__ __align__(16) unsigned short As[4][8192];   // 4 slots x 256rows(paired) x 32k
    __shared__ __align__(16) unsigned short Bs[4][8192];

    const int tid  = threadIdx.x;
    const int wave = tid >> 6;
    const int lane = tid & 63;

    // XCD-aware bijective swizzle (grid = mtiles*64, always % 8 == 0)
    const int nwg = mtiles * 64;
    const int cpx = nwg >> 3;
    const int bid = blockIdx.x;
    const int vid = (bid & 7) * cpx + (bid >> 3);
    const int bn  = vid & 63;           // dict tile of 256
    const int bm  = vid >> 6;           // token tile of 256

    const int wm = wave >> 2;           // 0..1  (M half)
    const int wn = wave & 3;            // 0..3  (N quarter)
    const int fr = lane & 15;
    const int kg = lane >> 4;

    // ---- staging source (per-thread, pre-swizzled so LDS dest stays linear) ----
    // LDS linear slot q = tid*16 (+ round*8192); paired layout: LDS row R holds
    // M-rows 2R (bytes 0-63) and 2R+1 (bytes 64-127), swizzle byte ^= (R&7)<<4.
    const int sR   = tid >> 3;                          // LDS row within round
    const int sinp = ((tid & 7) * 16) ^ ((sR & 7) << 4);
    const int smr  = 2 * sR + (sinp >> 6);              // M-row within round
    const int skb  = sinp & 63;                         // k byte
    const char* pA = (const char*)(A + (size_t)bm * 256 * D_MODEL) + (size_t)smr * (D_MODEL * 2) + skb;
    const char* pB = (const char*)(B + (size_t)bn * 256 * D_MODEL) + (size_t)smr * (D_MODEL * 2) + skb;

    // ---- ds_read per-thread base offsets (bytes); frag (mh,i): + mh*4096 + i*1024
    const int swz = ((((fr & 1) << 6) | (kg << 4)) ^ (((fr >> 1) & 7) << 4));
    const int aob = (wm * 64 + (fr >> 1)) * 128 + swz;
    const int bob = (wn * 32 + (fr >> 1)) * 128 + swz;

    floatx4 acc[8][4];
    #pragma unroll
    for (int i = 0; i < 8; ++i)
        #pragma unroll
        for (int j = 0; j < 4; ++j) acc[i][j] = floatx4{0.f, 0.f, 0.f, 0.f};

    // ---- prologue: stage tiles 0..2 (ring slots 0..2), tile0 guaranteed landed
    STAGE_A(0, 0); STAGE_B(0, 0);
    STAGE_A(1, 1); STAGE_B(1, 1);
    STAGE_A(2, 2); STAGE_B(2, 2);
    TILE_CLOSE(8)

    // ---- main loop: 32 K-tiles of 32; stage tile T+3 into slot (T+3)&3 = (T-1)&3
    #pragma unroll 1
    for (int T = 0; T < 29; ++T) {
        TILE_BODY(T, true)
        TILE_CLOSE(8)
    }
    TILE_BODY(29, false)
    TILE_CLOSE(4)
    TILE_BODY(30, false)
    TILE_CLOSE(0)
    TILE_BODY(31, false)

    // ---- epilogue: C bf16 write + per-128-col tile-max ----
    __syncthreads();
    unsigned int* rmax = (unsigned int*)&As[0][0];     // 512 entries: [row][half]
    rmax[tid] = 0;
    __syncthreads();

    const int col  = lane & 15;
    const int rq   = lane >> 4;
    const int half = wn >> 1;                          // 128-col tile within block
    const size_t colbase = (size_t)bn * 256 + wn * 64 + col;

    #pragma unroll
    for (int mf = 0; mf < 8; ++mf) {
        const int rowl = wm * 128 + mf * 16 + rq * 4;
        unsigned int rm[4] = {0, 0, 0, 0};
        #pragma unroll
        for (int nf = 0; nf < 4; ++nf) {
            unsigned short* cp = C + (size_t)(bm * 256 + rowl) * DICT + colbase + nf * 16;
            #pragma unroll
            for (int r = 0; r < 4; ++r) {
                const unsigned short bfv = f2bf(acc[mf][nf][r]);
                cp[(size_t)r * DICT] = bfv;
                rm[r] = max(rm[r], (unsigned int)(bfv ^ 0x8000u));
            }
        }
        #pragma unroll
        for (int r = 0; r < 4; ++r) {
            unsigned int m = rm[r];
            m = max(m, (unsigned int)__shfl_xor((int)m, 1, 64));
            m = max(m, (unsigned int)__shfl_xor((int)m, 2, 64));
            m = max(m, (unsigned int)__shfl_xor((int)m, 4, 64));
            m = max(m, (unsigned int)__shfl_xor((int)m, 8, 64));
            if (col == 0) atomicMax(&rmax[(rowl + r) * 2 + half], m);
        }
    }
    __syncthreads();
    {
        const int row = tid >> 1;
        tmax[(size_t)(bm * 256 + row) * NTILE + bn * 2 + (tid & 1)] = (unsigned short)rmax[tid];
    }
}

#undef TILE_BODY
#undef TILE_CLOSE
#undef MFMA4
#undef STAGE_A
#undef STAGE_B

// ---------------------------------------------------------------------------
// Fused select + refine + offset. One block (256 thr) per token.
// ---------------------------------------------------------------------------
__device__ __forceinline__ bool tk_better(float v1, int i1, float v2, int i2) {
    return (v1 > v2) || (v1 == v2 && i1 < i2);
}

__global__ __launch_bounds__(256) void ssod_select_refine(const unsigned short* __restrict__ coeffs,
                                                          const unsigned short* __restrict__ tmax,
                                                          const float* __restrict__ x,
                                                          const float* __restrict__ Wenc,
                                                          const float* __restrict__ Wdict,
                                                          float* __restrict__ outp,
                                                          float* __restrict__ tsum,
                                                          int tokBase) {
    const int tl   = blockIdx.x;          // chunk-local token
    const int t    = tokBase + tl;        // global token
    const int tid  = threadIdx.x;
    const int lane = tid & 63;
    const int wave = tid >> 6;

    __shared__ unsigned int keys[128];
    __shared__ int   tlist[64];
    __shared__ int   ncnt, kcnt;
    __shared__ unsigned int sTau;
    __shared__ float xs[D_MODEL];
    __shared__ int   cidx[NCAND];
    __shared__ float cval[NCAND];
    __shared__ float sval[TOPK];
    __shared__ int   sidx[TOPK];

    // stage x into LDS (used in phase B)
    ((float4*)xs)[tid] = ((const float4*)(x + (size_t)t * D_MODEL))[tid];
    if (tid == 0) { ncnt = 0; kcnt = 0; }
    __syncthreads();

    // ---- tau: 16th-largest of the 128 tile maxes (wave 0, 2-reg bitonic) ----
    const unsigned short* tmrow = tmax + (size_t)t * NTILE;
    if (wave == 0) {
        const unsigned int u = ((const unsigned int*)tmrow)[lane];
        unsigned int v0 = u & 0xFFFFu, v1 = u >> 16;
        for (int k = 2; k <= 128; k <<= 1) {
            for (int j = k >> 1; j >= 1; j >>= 1) {
                if (j == 64) {
                    const unsigned int a = max(v0, v1), b = min(v0, v1);
                    v0 = a; v1 = b;
                } else {
                    const unsigned int p0 = __shfl_xor(v0, j, 64);
                    const unsigned int p1 = __shfl_xor(v1, j, 64);
                    const bool tm0 = ((lane & j) == 0) ^ ((( lane      ) & k) != 0);
                    const bool tm1 = ((lane & j) == 0) ^ (((lane + 64) & k) != 0);
                    v0 = tm0 ? max(v0, p0) : min(v0, p0);
                    v1 = tm1 ? max(v1, p1) : min(v1, p1);
                }
            }
        }
        if (lane == 15) sTau = v0;       // descending: lane 15 = 16th largest
    }
    __syncthreads();
    const unsigned int tau = sTau;

    // ---- qualifying tile list (max >= tau): >=16 tiles by construction ----
    if (tid < NTILE) {
        if ((unsigned int)tmrow[tid] >= tau) {
            const int p = atomicAdd(&ncnt, 1);
            if (p < 64) tlist[p] = tid;
        }
    }
    __syncthreads();
    const int nq = min(ncnt, 64);

    // ---- collect elems >= tau from qualifying tiles ----
    const uint4* row4 = (const uint4*)(coeffs + (size_t)tl * DICT);
    for (int j = tid; j < nq * 16; j += 256) {
        const int tile = tlist[j >> 4];
        const int sub  = j & 15;
        const uint4 p = row4[tile * 16 + sub];
        unsigned int w[4] = {p.x ^ 0x80008000u, p.y ^ 0x80008000u,
                             p.z ^ 0x80008000u, p.w ^ 0x80008000u};
        const int base = tile * 128 + sub * 8;
        #pragma unroll
        for (int h = 0; h < 4; ++h) {
            const unsigned int lo = w[h] & 0xFFFFu, hi = w[h] >> 16;
            if (lo >= tau) {
                const int q = atomicAdd(&kcnt, 1);
                if (q < 128) keys[q] = (lo << 16) | (unsigned)(16383 - (base + h * 2));
            }
            if (hi >= tau) {
                const int q = atomicAdd(&kcnt, 1);
                if (q < 128) keys[q] = (hi << 16) | (unsigned)(16383 - (base + h * 2 + 1));
            }
        }
    }
    __syncthreads();
    const int m = min(kcnt, 128);
    for (int i = m + tid; i < 128; i += 256) keys[i] = 0;
    __syncthreads();

    // ---- wave 0: bitonic sort 128 keys desc, emit top-16 indices ----
    if (wave == 0) {
        unsigned int v0 = keys[lane], v1 = keys[lane + 64];
        for (int k = 2; k <= 128; k <<= 1) {
            for (int j = k >> 1; j >= 1; j >>= 1) {
                if (j == 64) {
                    const unsigned int a = max(v0, v1), b = min(v0, v1);
                    v0 = a; v1 = b;
                } else {
                    const unsigned int p0 = __shfl_xor(v0, j, 64);
                    const unsigned int p1 = __shfl_xor(v1, j, 64);
                    const bool tm0 = ((lane & j) == 0) ^ ((( lane      ) & k) != 0);
                    const bool tm1 = ((lane & j) == 0) ^ (((lane + 64) & k) != 0);
                    v0 = tm0 ? max(v0, p0) : min(v0, p0);
                    v1 = tm1 ? max(v1, p1) : min(v1, p1);
                }
            }
        }
        if (lane < NCAND) cidx[lane] = 16383 - (int)(v0 & 0xFFFFu);
    }
    __syncthreads();

    // ---- Phase B: fp32 refine of 16 candidates (4 per wave, loads up front) ----
    const float4* xs4 = (const float4*)xs;
    float4 xv[4];
    #pragma unroll
    for (int q = 0; q < 4; ++q) xv[q] = xs4[q * 64 + lane];

    float4 wv[4][4];
    #pragma unroll
    for (int s = 0; s < 4; ++s) {
        const float4* wr4 = (const float4*)(Wenc + (size_t)cidx[s * 4 + wave] * D_MODEL);
        #pragma unroll
        for (int q = 0; q < 4; ++q) wv[s][q] = wr4[q * 64 + lane];
    }
    #pragma unroll
    for (int s = 0; s < 4; ++s) {
        float sum = 0.f;
        #pragma unroll
        for (int q = 0; q < 4; ++q)
            sum += xv[q].x * wv[s][q].x + xv[q].y * wv[s][q].y +
                   xv[q].z * wv[s][q].z + xv[q].w * wv[s][q].w;
        #pragma unroll
        for (int off = 32; off > 0; off >>= 1) sum += __shfl_down(sum, off, 64);
        if (lane == 0) cval[s * 4 + wave] = sum;
    }
    __syncthreads();

    // ---- parallel rank-based exact top-8 ----
    if (tid < NCAND) {
        const float v = cval[tid];
        const int  ix = cidx[tid];
        int rank = 0;
        #pragma unroll
        for (int j = 0; j < NCAND; ++j)
            rank += (j != tid) && tk_better(cval[j], cidx[j], v, ix);
        if (rank < TOPK) { sval[rank] = v; sidx[rank] = ix; }
    }
    __syncthreads();
    if (tid == 0) {
        float s = 0.f;
        #pragma unroll
        for (int k = 0; k < TOPK; ++k) s += fabsf(sval[k]);
        tsum[t] = s;
    }

    // ---- offset ----
    const int dd = tid * 4;
    float4 a = make_float4(0.f, 0.f, 0.f, 0.f);
    #pragma unroll
    for (int k = 0; k < TOPK; ++k) {
        const float4 r = *(const float4*)(Wdict + (size_t)sidx[k] * D_MODEL + dd);
        const float s = sval[k];
        a.x += s * r.x; a.y += s * r.y; a.z += s * r.z; a.w += s * r.w;
    }
    *(float4*)(outp + (size_t)t * D_MODEL + dd) = a;
}

// ---------------------------------------------------------------------------
// loss = sum(tsum) / (NTOK*DICT)
// ---------------------------------------------------------------------------
__global__ __launch_bounds__(256) void ssod_loss(const float* __restrict__ tsum,
                                                 float* __restrict__ out) {
    float s = 0.f;
    for (int i = threadIdx.x; i < NTOK; i += 256) s += tsum[i];
    #pragma unroll
    for (int off = 32; off > 0; off >>= 1) s += __shfl_down(s, off, 64);
    __shared__ float wsum[4];
    if ((threadIdx.x & 63) == 0) wsum[threadIdx.x >> 6] = s;
    __syncthreads();
    if (threadIdx.x == 0) {
        const float tot = wsum[0] + wsum[1] + wsum[2] + wsum[3];
        out[(size_t)NTOK * D_MODEL] = tot / (float)COEFF_COUNT;
    }
}

// ---------------------------------------------------------------------------
extern "C" void kernel_launch(void* const* d_in, const int* in_sizes, int n_in,
                              void* d_out, int out_size, void* d_ws, size_t ws_size,
                              hipStream_t stream) {
    const float* x     = (const float*)d_in[0];   // [4096,1024]
    const float* Wenc  = (const float*)d_in[1];   // [16384,1024]
    const float* Wdict = (const float*)d_in[2];   // [16384,1024]
    float* out = (float*)d_out;

    char* ws = (char*)d_ws;
    size_t off = 0;
    unsigned short* xbf  = (unsigned short*)(ws + off); off += (size_t)NTOK * D_MODEL * 2;  // 8 MB
    unsigned short* wbf  = (unsigned short*)(ws + off); off += (size_t)DICT * D_MODEL * 2;  // 33.6 MB
    unsigned short* tmax = (unsigned short*)(ws + off); off += (size_t)NTOK * NTILE * 2;    // 1 MB
    float* tsum = (float*)(ws + off);                   off += (size_t)NTOK * 4;            // 16 KB
    unsigned short* coeffs = (unsigned short*)(ws + off);

    // largest token chunk whose bf16 coeff buffer fits remaining ws
    const size_t remain = (ws_size > off) ? (ws_size - off) : 0;
    int chunk = 512;
    if (remain >= (size_t)4096 * DICT * 2) chunk = 4096;
    else if (remain >= (size_t)2048 * DICT * 2) chunk = 2048;
    else if (remain >= (size_t)1024 * DICT * 2) chunk = 1024;

    const int nx4 = NTOK * D_MODEL / 4;
    const int nw4 = DICT * D_MODEL / 4;
    ssod_cvt2<<<(nx4 + nw4 + 255) / 256, 256, 0, stream>>>(
        (const float4*)x, (ushort4*)xbf, nx4, (const float4*)Wenc, (ushort4*)wbf, nw4);

    for (int tokBase = 0; tokBase < NTOK; tokBase += chunk) {
        const int mtiles = chunk / 256;
        ssod_gemm_bf16<<<mtiles * 64, 512, 0, stream>>>(xbf + (size_t)tokBase * D_MODEL, wbf, coeffs,
                                                        tmax + (size_t)tokBase * NTILE, mtiles);
        ssod_select_refine<<<chunk, 256, 0, stream>>>(coeffs, tmax, x, Wenc, Wdict, out, tsum, tokBase);
    }
    ssod_loss<<<1, 256, 0, stream>>>(tsum, out);
}

// Round 2
// 360.121 us; speedup vs baseline: 1.1041x; 1.1041x over previous
//
#include <hip/hip_runtime.h>
#include <float.h>
#include <stdint.h>

constexpr int D_MODEL = 1024;
constexpr int DICT    = 16384;
constexpr int TOPK    = 8;
constexpr int NCAND   = 16;
constexpr int NTOK    = 4096;      // B*T
constexpr int NTILE   = 128;       // DICT / 128
constexpr long long COEFF_COUNT = (long long)NTOK * DICT;

typedef __attribute__((ext_vector_type(8))) __bf16 bf16x8;
typedef __attribute__((ext_vector_type(4))) float  floatx4;

__device__ __forceinline__ unsigned short f2bf(float f) {
    unsigned int u = __float_as_uint(f);
    u = u + 0x7fffu + ((u >> 16) & 1u);     // RNE
    return (unsigned short)(u >> 16);
}

__device__ __forceinline__ void async16(void* lds, const void* g) {
    __builtin_amdgcn_global_load_lds(
        (__attribute__((address_space(1))) void*)g,
        (__attribute__((address_space(3))) void*)lds, 16, 0, 0);
}

// ---------------------------------------------------------------------------
// fused fp32 -> bf16 convert for x and Wenc (one dispatch)
// ---------------------------------------------------------------------------
__global__ __launch_bounds__(256) void ssod_cvt2(const float4* __restrict__ xs, ushort4* __restrict__ xd, int nx4,
                                                 const float4* __restrict__ ws, ushort4* __restrict__ wd, int nw4) {
    const int i = blockIdx.x * 256 + threadIdx.x;
    if (i < nx4) {
        const float4 v = xs[i];
        ushort4 o; o.x = f2bf(v.x); o.y = f2bf(v.y); o.z = f2bf(v.z); o.w = f2bf(v.w);
        xd[i] = o;
    } else {
        const int j = i - nx4;
        if (j < nw4) {
            const float4 v = ws[j];
            ushort4 o; o.x = f2bf(v.x); o.y = f2bf(v.y); o.z = f2bf(v.z); o.w = f2bf(v.w);
            wd[j] = o;
        }
    }
}

// ---------------------------------------------------------------------------
// 256x256-tile, 8-wave bf16 MFMA GEMM. Software-pipelined: ONE barrier per
// K-tile; fragment regs double-buffered (RA/RB) so next tile's ds_reads issue
// between this tile's two MFMA clusters. Counted vmcnt (8 steady / 4 / 0 tail).
// Swapped MFMA operands -> D[dict][token]: packed dwordx2 C-stores.
// XCD bn-partition: XCD x owns dict tiles [x*8, x*8+8) (4MB B slice = one L2).
// ---------------------------------------------------------------------------
constexpr size_t R1OFF = (size_t)128 * (D_MODEL * 2);   // +128 rows in global

#define STAGE_A(buf_, t_) do {                                               \
    const char* s_ = pA + (size_t)(t_) * 64;                                 \
    char* d_ = (char*)&As[(buf_)][0] + wave * 1024;                          \
    async16(d_, s_); async16(d_ + 8192, s_ + R1OFF);                         \
} while (0)

#define STAGE_B(buf_, t_) do {                                               \
    const char* s_ = pB + (size_t)(t_) * 64;                                 \
    char* d_ = (char*)&Bs[(buf_)][0] + wave * 1024;                          \
    async16(d_, s_); async16(d_ + 8192, s_ + R1OFF);                         \
} while (0)

#define LOADFRAGS(P, buf_) do {                                              \
    const char* ab_ = (const char*)As + (buf_) * 16384 + aob;                \
    const char* bb_ = (const char*)Bs + (buf_) * 16384 + bob;                \
    P##af0 = *(const bf16x8*)(ab_);                                          \
    P##af1 = *(const bf16x8*)(ab_ + 1024);                                   \
    P##af2 = *(const bf16x8*)(ab_ + 2048);                                   \
    P##af3 = *(const bf16x8*)(ab_ + 3072);                                   \
    P##af4 = *(const bf16x8*)(ab_ + 4096);                                   \
    P##af5 = *(const bf16x8*)(ab_ + 5120);                                   \
    P##af6 = *(const bf16x8*)(ab_ + 6144);                                   \
    P##af7 = *(const bf16x8*)(ab_ + 7168);                                   \
    P##bq0 = *(const bf16x8*)(bb_);                                          \
    P##bq1 = *(const bf16x8*)(bb_ + 1024);                                   \
    P##bq2 = *(const bf16x8*)(bb_ + 2048);                                   \
    P##bq3 = *(const bf16x8*)(bb_ + 3072);                                   \
} while (0)

// swapped operands: A-op = dict frag (bq), B-op = token frag (af)
// -> D row = dict offset (regs), D col = token offset (lane&15)
#define MROW(P, AF, m_)                                                                     \
    acc[m_][0] = __builtin_amdgcn_mfma_f32_16x16x32_bf16(P##bq0, AF, acc[m_][0], 0, 0, 0);  \
    acc[m_][1] = __builtin_amdgcn_mfma_f32_16x16x32_bf16(P##bq1, AF, acc[m_][1], 0, 0, 0);  \
    acc[m_][2] = __builtin_amdgcn_mfma_f32_16x16x32_bf16(P##bq2, AF, acc[m_][2], 0, 0, 0);  \
    acc[m_][3] = __builtin_amdgcn_mfma_f32_16x16x32_bf16(P##bq3, AF, acc[m_][3], 0, 0, 0);

#define C1(P) MROW(P, P##af0, 0) MROW(P, P##af1, 1) MROW(P, P##af2, 2) MROW(P, P##af3, 3)
#define C2(P) MROW(P, P##af4, 4) MROW(P, P##af5, 5) MROW(P, P##af6, 6) MROW(P, P##af7, 7)

#define TILE(T_, CONS, LOAD, DOSTAGE, VMI) do {                              \
    if (DOSTAGE) {                                                           \
        STAGE_A(((T_) + 3) & 3, (T_) + 3);                                   \
        STAGE_B(((T_) + 3) & 3, (T_) + 3);                                   \
    }                                                                        \
    asm volatile("s_waitcnt vmcnt(" #VMI ")" ::: "memory");                  \
    asm volatile("s_barrier" ::: "memory");                                  \
    __builtin_amdgcn_s_setprio(1);                                           \
    C1(CONS)                                                                 \
    LOADFRAGS(LOAD, ((T_) + 1) & 3);                                         \
    C2(CONS)                                                                 \
    __builtin_amdgcn_s_setprio(0);                                           \
} while (0)

__global__ __launch_bounds__(512, 2) void ssod_gemm_bf16(const unsigned short* __restrict__ A,
                                                         const unsigned short* __restrict__ B,
                                                         unsigned short* __restrict__ C,
                                                         unsigned short* __restrict__ tmax) {
    __shared__ __align__(16) unsigned short As[4][8192];   // 4 ring slots x 16KB
    __shared__ __align__(16) unsigned short Bs[4][8192];

    const int tid  = threadIdx.x;
    const int wave = tid >> 6;
    const int lane = tid & 63;

    // XCD bn-partition: XCD x = bid&7 owns bn in [x*8, x*8+8); bm sweeps slow.
    const int bid = blockIdx.x;
    const int bn  = (bid & 7) * 8 + ((bid >> 3) & 7);
    const int bm  = bid >> 6;

    const int wm = wave >> 2;           // 0..1  (token half, 128 rows)
    const int wn = wave & 3;            // 0..3  (dict quarter, 64 cols)
    const int fr = lane & 15;
    const int kg = lane >> 4;

    // ---- staging source (per-thread, pre-swizzled so LDS dest stays linear) ----
    const int sR   = tid >> 3;                          // LDS row within round
    const int sinp = ((tid & 7) * 16) ^ ((sR & 7) << 4);
    const int smr  = 2 * sR + (sinp >> 6);              // M-row within round
    const int skb  = sinp & 63;                         // k byte
    const char* pA = (const char*)(A + (size_t)bm * 256 * D_MODEL) + (size_t)smr * (D_MODEL * 2) + skb;
    const char* pB = (const char*)(B + (size_t)bn * 256 * D_MODEL) + (size_t)smr * (D_MODEL * 2) + skb;

    // ---- ds_read per-thread base offsets (bytes) ----
    const int swz = ((((fr & 1) << 6) | (kg << 4)) ^ (((fr >> 1) & 7) << 4));
    const int aob = (wm * 64 + (fr >> 1)) * 128 + swz;
    const int bob = (wn * 32 + (fr >> 1)) * 128 + swz;

    floatx4 acc[8][4];
    #pragma unroll
    for (int i = 0; i < 8; ++i)
        #pragma unroll
        for (int j = 0; j < 4; ++j) acc[i][j] = floatx4{0.f, 0.f, 0.f, 0.f};

    bf16x8 RA_af0, RA_af1, RA_af2, RA_af3, RA_af4, RA_af5, RA_af6, RA_af7;
    bf16x8 RA_bq0, RA_bq1, RA_bq2, RA_bq3;
    bf16x8 RB_af0, RB_af1, RB_af2, RB_af3, RB_af4, RB_af5, RB_af6, RB_af7;
    bf16x8 RB_bq0, RB_bq1, RB_bq2, RB_bq3;

    // ---- prologue: stage tiles 0..2 (12 loads), publish slot 0, preload frags
    STAGE_A(0, 0); STAGE_B(0, 0);
    STAGE_A(1, 1); STAGE_B(1, 1);
    STAGE_A(2, 2); STAGE_B(2, 2);
    asm volatile("s_waitcnt vmcnt(8)" ::: "memory");
    asm volatile("s_barrier" ::: "memory");
    LOADFRAGS(RA_, 0);

    // ---- main loop: 32 K-tiles of 32; one barrier per tile ----
    #pragma unroll 1
    for (int T = 0; T < 28; T += 2) {
        TILE(T,     RA_, RB_, true, 8);
        TILE(T + 1, RB_, RA_, true, 8);
    }
    TILE(28, RA_, RB_, true,  8);
    TILE(29, RB_, RA_, false, 4);
    TILE(30, RA_, RB_, false, 0);
    __builtin_amdgcn_s_setprio(1);
    C1(RB_)
    C2(RB_)
    __builtin_amdgcn_s_setprio(0);

    // ---- epilogue: packed dwordx2 C-write + per-128-col tile-max ----
    __syncthreads();
    unsigned int* rmax = (unsigned int*)&As[0][0];     // 512 entries: [token][half]
    rmax[tid] = 0;
    __syncthreads();

    const int tcol  = lane & 15;                       // token offset in frag
    const int rq4   = (lane >> 4) * 4;                 // dict quad base
    const int half  = wn >> 1;                         // 128-col tile within block
    const int dbase = bn * 256 + wn * 64 + rq4;

    #pragma unroll
    for (int mf = 0; mf < 8; ++mf) {
        const int tok = wm * 128 + mf * 16 + tcol;     // block-local token
        unsigned int tm = 0;
        #pragma unroll
        for (int nf = 0; nf < 4; ++nf) {
            const floatx4 a = acc[mf][nf];
            const unsigned int b0 = f2bf(a[0]), b1 = f2bf(a[1]);
            const unsigned int b2 = f2bf(a[2]), b3 = f2bf(a[3]);
            tm = max(tm, max(max(b0 ^ 0x8000u, b1 ^ 0x8000u),
                             max(b2 ^ 0x8000u, b3 ^ 0x8000u)));
            uint2 pk; pk.x = b0 | (b1 << 16); pk.y = b2 | (b3 << 16);
            *(uint2*)(C + (size_t)(bm * 256 + tok) * DICT + dbase + nf * 16) = pk;
        }
        tm = max(tm, (unsigned int)__shfl_xor((int)tm, 16, 64));
        tm = max(tm, (unsigned int)__shfl_xor((int)tm, 32, 64));
        if (lane < 16) atomicMax(&rmax[tok * 2 + half], tm);
    }
    __syncthreads();
    tmax[(size_t)(bm * 256 + (tid >> 1)) * NTILE + bn * 2 + (tid & 1)] =
        (unsigned short)rmax[tid];
}

#undef TILE
#undef C1
#undef C2
#undef MROW
#undef LOADFRAGS
#undef STAGE_A
#undef STAGE_B

// ---------------------------------------------------------------------------
// Fused select + refine + offset. One block (256 thr) per token.
// ---------------------------------------------------------------------------
__device__ __forceinline__ bool tk_better(float v1, int i1, float v2, int i2) {
    return (v1 > v2) || (v1 == v2 && i1 < i2);
}

__global__ __launch_bounds__(256) void ssod_select_refine(const unsigned short* __restrict__ coeffs,
                                                          const unsigned short* __restrict__ tmax,
                                                          const float* __restrict__ x,
                                                          const float* __restrict__ Wenc,
                                                          const float* __restrict__ Wdict,
                                                          float* __restrict__ outp,
                                                          float* __restrict__ tsum,
                                                          int tokBase) {
    const int tl   = blockIdx.x;          // chunk-local token
    const int t    = tokBase + tl;        // global token
    const int tid  = threadIdx.x;
    const int lane = tid & 63;
    const int wave = tid >> 6;

    __shared__ unsigned int keys[128];
    __shared__ int   tlist[64];
    __shared__ int   ncnt, kcnt;
    __shared__ unsigned int sTau;
    __shared__ float xs[D_MODEL];
    __shared__ int   cidx[NCAND];
    __shared__ float cval[NCAND];
    __shared__ float sval[TOPK];
    __shared__ int   sidx[TOPK];

    // stage x into LDS (used in phase B)
    ((float4*)xs)[tid] = ((const float4*)(x + (size_t)t * D_MODEL))[tid];
    if (tid == 0) { ncnt = 0; kcnt = 0; }
    __syncthreads();

    // ---- tau: 16th-largest of the 128 tile maxes (wave 0, 2-reg bitonic) ----
    const unsigned short* tmrow = tmax + (size_t)t * NTILE;
    if (wave == 0) {
        const unsigned int u = ((const unsigned int*)tmrow)[lane];
        unsigned int v0 = u & 0xFFFFu, v1 = u >> 16;
        for (int k = 2; k <= 128; k <<= 1) {
            for (int j = k >> 1; j >= 1; j >>= 1) {
                if (j == 64) {
                    const unsigned int a = max(v0, v1), b = min(v0, v1);
                    v0 = a; v1 = b;
                } else {
                    const unsigned int p0 = __shfl_xor(v0, j, 64);
                    const unsigned int p1 = __shfl_xor(v1, j, 64);
                    const bool tm0 = ((lane & j) == 0) ^ ((( lane      ) & k) != 0);
                    const bool tm1 = ((lane & j) == 0) ^ (((lane + 64) & k) != 0);
                    v0 = tm0 ? max(v0, p0) : min(v0, p0);
                    v1 = tm1 ? max(v1, p1) : min(v1, p1);
                }
            }
        }
        if (lane == 15) sTau = v0;       // descending: lane 15 = 16th largest
    }
    __syncthreads();
    const unsigned int tau = sTau;

    // ---- qualifying tile list (max >= tau): >=16 tiles by construction ----
    if (tid < NTILE) {
        if ((unsigned int)tmrow[tid] >= tau) {
            const int p = atomicAdd(&ncnt, 1);
            if (p < 64) tlist[p] = tid;
        }
    }
    __syncthreads();
    const int nq = min(ncnt, 64);

    // ---- collect elems >= tau from qualifying tiles ----
    const uint4* row4 = (const uint4*)(coeffs + (size_t)tl * DICT);
    for (int j = tid; j < nq * 16; j += 256) {
        const int tile = tlist[j >> 4];
        const int sub  = j & 15;
        const uint4 p = row4[tile * 16 + sub];
        unsigned int w[4] = {p.x ^ 0x80008000u, p.y ^ 0x80008000u,
                             p.z ^ 0x80008000u, p.w ^ 0x80008000u};
        const int base = tile * 128 + sub * 8;
        #pragma unroll
        for (int h = 0; h < 4; ++h) {
            const unsigned int lo = w[h] & 0xFFFFu, hi = w[h] >> 16;
            if (lo >= tau) {
                const int q = atomicAdd(&kcnt, 1);
                if (q < 128) keys[q] = (lo << 16) | (unsigned)(16383 - (base + h * 2));
            }
            if (hi >= tau) {
                const int q = atomicAdd(&kcnt, 1);
                if (q < 128) keys[q] = (hi << 16) | (unsigned)(16383 - (base + h * 2 + 1));
            }
        }
    }
    __syncthreads();
    const int m = min(kcnt, 128);
    for (int i = m + tid; i < 128; i += 256) keys[i] = 0;
    __syncthreads();

    // ---- wave 0: bitonic sort 128 keys desc, emit top-16 indices ----
    if (wave == 0) {
        unsigned int v0 = keys[lane], v1 = keys[lane + 64];
        for (int k = 2; k <= 128; k <<= 1) {
            for (int j = k >> 1; j >= 1; j >>= 1) {
                if (j == 64) {
                    const unsigned int a = max(v0, v1), b = min(v0, v1);
                    v0 = a; v1 = b;
                } else {
                    const unsigned int p0 = __shfl_xor(v0, j, 64);
                    const unsigned int p1 = __shfl_xor(v1, j, 64);
                    const bool tm0 = ((lane & j) == 0) ^ ((( lane      ) & k) != 0);
                    const bool tm1 = ((lane & j) == 0) ^ (((lane + 64) & k) != 0);
                    v0 = tm0 ? max(v0, p0) : min(v0, p0);
                    v1 = tm1 ? max(v1, p1) : min(v1, p1);
                }
            }
        }
        if (lane < NCAND) cidx[lane] = 16383 - (int)(v0 & 0xFFFFu);
    }
    __syncthreads();

    // ---- Phase B: fp32 refine of 16 candidates (4 per wave, loads up front) ----
    const float4* xs4 = (const float4*)xs;
    float4 xv[4];
    #pragma unroll
    for (int q = 0; q < 4; ++q) xv[q] = xs4[q * 64 + lane];

    float4 wv[4][4];
    #pragma unroll
    for (int s = 0; s < 4; ++s) {
        const float4* wr4 = (const float4*)(Wenc + (size_t)cidx[s * 4 + wave] * D_MODEL);
        #pragma unroll
        for (int q = 0; q < 4; ++q) wv[s][q] = wr4[q * 64 + lane];
    }
    #pragma unroll
    for (int s = 0; s < 4; ++s) {
        float sum = 0.f;
        #pragma unroll
        for (int q = 0; q < 4; ++q)
            sum += xv[q].x * wv[s][q].x + xv[q].y * wv[s][q].y +
                   xv[q].z * wv[s][q].z + xv[q].w * wv[s][q].w;
        #pragma unroll
        for (int off = 32; off > 0; off >>= 1) sum += __shfl_down(sum, off, 64);
        if (lane == 0) cval[s * 4 + wave] = sum;
    }
    __syncthreads();

    // ---- parallel rank-based exact top-8 ----
    if (tid < NCAND) {
        const float v = cval[tid];
        const int  ix = cidx[tid];
        int rank = 0;
        #pragma unroll
        for (int j = 0; j < NCAND; ++j)
            rank += (j != tid) && tk_better(cval[j], cidx[j], v, ix);
        if (rank < TOPK) { sval[rank] = v; sidx[rank] = ix; }
    }
    __syncthreads();
    if (tid == 0) {
        float s = 0.f;
        #pragma unroll
        for (int k = 0; k < TOPK; ++k) s += fabsf(sval[k]);
        tsum[t] = s;
    }

    // ---- offset ----
    const int dd = tid * 4;
    float4 a = make_float4(0.f, 0.f, 0.f, 0.f);
    #pragma unroll
    for (int k = 0; k < TOPK; ++k) {
        const float4 r = *(const float4*)(Wdict + (size_t)sidx[k] * D_MODEL + dd);
        const float s = sval[k];
        a.x += s * r.x; a.y += s * r.y; a.z += s * r.z; a.w += s * r.w;
    }
    *(float4*)(outp + (size_t)t * D_MODEL + dd) = a;
}

// ---------------------------------------------------------------------------
// loss = sum(tsum) / (NTOK*DICT)
// ---------------------------------------------------------------------------
__global__ __launch_bounds__(256) void ssod_loss(const float* __restrict__ tsum,
                                                 float* __restrict__ out) {
    float s = 0.f;
    for (int i = threadIdx.x; i < NTOK; i += 256) s += tsum[i];
    #pragma unroll
    for (int off = 32; off > 0; off >>= 1) s += __shfl_down(s, off, 64);
    __shared__ float wsum[4];
    if ((threadIdx.x & 63) == 0) wsum[threadIdx.x >> 6] = s;
    __syncthreads();
    if (threadIdx.x == 0) {
        const float tot = wsum[0] + wsum[1] + wsum[2] + wsum[3];
        out[(size_t)NTOK * D_MODEL] = tot / (float)COEFF_COUNT;
    }
}

// ---------------------------------------------------------------------------
extern "C" void kernel_launch(void* const* d_in, const int* in_sizes, int n_in,
                              void* d_out, int out_size, void* d_ws, size_t ws_size,
                              hipStream_t stream) {
    const float* x     = (const float*)d_in[0];   // [4096,1024]
    const float* Wenc  = (const float*)d_in[1];   // [16384,1024]
    const float* Wdict = (const float*)d_in[2];   // [16384,1024]
    float* out = (float*)d_out;

    char* ws = (char*)d_ws;
    size_t off = 0;
    unsigned short* xbf  = (unsigned short*)(ws + off); off += (size_t)NTOK * D_MODEL * 2;  // 8 MB
    unsigned short* wbf  = (unsigned short*)(ws + off); off += (size_t)DICT * D_MODEL * 2;  // 33.6 MB
    unsigned short* tmax = (unsigned short*)(ws + off); off += (size_t)NTOK * NTILE * 2;    // 1 MB
    float* tsum = (float*)(ws + off);                   off += (size_t)NTOK * 4;            // 16 KB
    unsigned short* coeffs = (unsigned short*)(ws + off);

    // largest token chunk whose bf16 coeff buffer fits remaining ws
    const size_t remain = (ws_size > off) ? (ws_size - off) : 0;
    int chunk = 512;
    if (remain >= (size_t)4096 * DICT * 2) chunk = 4096;
    else if (remain >= (size_t)2048 * DICT * 2) chunk = 2048;
    else if (remain >= (size_t)1024 * DICT * 2) chunk = 1024;

    const int nx4 = NTOK * D_MODEL / 4;
    const int nw4 = DICT * D_MODEL / 4;
    ssod_cvt2<<<(nx4 + nw4 + 255) / 256, 256, 0, stream>>>(
        (const float4*)x, (ushort4*)xbf, nx4, (const float4*)Wenc, (ushort4*)wbf, nw4);

    for (int tokBase = 0; tokBase < NTOK; tokBase += chunk) {
        const int mtiles = chunk / 256;
        ssod_gemm_bf16<<<mtiles * 64, 512, 0, stream>>>(xbf + (size_t)tokBase * D_MODEL, wbf, coeffs,
                                                        tmax + (size_t)tokBase * NTILE);
        ssod_select_refine<<<chunk, 256, 0, stream>>>(coeffs, tmax, x, Wenc, Wdict, out, tsum, tokBase);
    }
    ssod_loss<<<1, 256, 0, stream>>>(tsum, out);
}